// Round 2
// baseline (386.060 us; speedup 1.0000x reference)
//
#include <hip/hip_runtime.h>

// ---------------------------------------------------------------------------
// Encoder layer on MI355X (gfx950). bf16 MFMA GEMMs + fp32 LN/softmax.
// B=4, S=2048, D=512, F=2048.
// Round 2: double-buffered prefetch GEMM (one barrier per K-step), scale in
// scores epilogue, stride params for GEMM.
// ---------------------------------------------------------------------------

typedef __attribute__((ext_vector_type(8))) short short8;
typedef __attribute__((ext_vector_type(4))) float f32x4;

__device__ __forceinline__ unsigned short f2bf(float f) {
    unsigned int u = __float_as_uint(f);
    unsigned int r = (u + 0x7FFFu + ((u >> 16) & 1u)) >> 16;
    return (unsigned short)r;
}

__device__ __forceinline__ void gload_lds16(const void* g, void* l) {
    __builtin_amdgcn_global_load_lds(
        (const __attribute__((address_space(1))) void*)g,
        (__attribute__((address_space(3))) void*)l, 16, 0, 0);
}

// ---------------------------------------------------------------------------
// cast fp32 -> bf16 (vectorized float4 -> 4x bf16)
// ---------------------------------------------------------------------------
__global__ __launch_bounds__(256) void cast_f32_bf16(
    const float* __restrict__ in, unsigned short* __restrict__ out, long n4) {
    long i = (long)blockIdx.x * blockDim.x + threadIdx.x;
    if (i < n4) {
        float4 v = ((const float4*)in)[i];
        ushort4 o;
        o.x = f2bf(v.x); o.y = f2bf(v.y); o.z = f2bf(v.z); o.w = f2bf(v.w);
        ((ushort4*)out)[i] = o;
    }
}

// ---------------------------------------------------------------------------
// transpose + cast: fp32 in[R][C] -> bf16 out[C][R]
// ---------------------------------------------------------------------------
__global__ __launch_bounds__(256) void transpose_cast_f32_bf16(
    const float* __restrict__ in, unsigned short* __restrict__ out, int R, int C) {
    __shared__ float t[32][33];
    int c0 = blockIdx.x * 32, r0 = blockIdx.y * 32;
    int x = threadIdx.x;
    for (int i = threadIdx.y; i < 32; i += 8)
        t[i][x] = in[(long)(r0 + i) * C + c0 + x];
    __syncthreads();
    for (int i = threadIdx.y; i < 32; i += 8)
        out[(long)(c0 + i) * R + r0 + x] = f2bf(t[x][i]);
}

// ---------------------------------------------------------------------------
// transpose bf16: in[R][C] (row stride inLd) -> out[C][R], batched over z
// ---------------------------------------------------------------------------
__global__ __launch_bounds__(256) void transpose_bf16(
    const unsigned short* __restrict__ in, unsigned short* __restrict__ out,
    int R, int C, int inLd, long inBatch, long outBatch) {
    __shared__ unsigned short t[32][33];
    long z = blockIdx.z;
    in += z * inBatch; out += z * outBatch;
    int c0 = blockIdx.x * 32, r0 = blockIdx.y * 32;
    int x = threadIdx.x;
    for (int i = threadIdx.y; i < 32; i += 8)
        t[i][x] = in[(long)(r0 + i) * inLd + c0 + x];
    __syncthreads();
    for (int i = threadIdx.y; i < 32; i += 8)
        out[(long)(c0 + i) * R + r0 + x] = t[x][i];
}

// ---------------------------------------------------------------------------
// bf16 nt-GEMM: C[M][N] = scale*(A[M][K] * BT[N][K]^T) + bias, opt relu.
// 128x128 tile, BK=32, 256 threads = 4 waves, each wave 64x64 (4x4 MFMA frags)
// Double-buffered global_load_lds prefetch: one barrier per K-step; the
// vmcnt(0) drain before the barrier lands AFTER the MFMAs, so the next
// tile's load latency hides under compute (critical at 1 block/CU grids).
// ---------------------------------------------------------------------------
template<int BIAS, int RELU, int OUT_BF16>
__global__ __launch_bounds__(256, 2) void gemm_nt(
    const unsigned short* __restrict__ A, const unsigned short* __restrict__ BT,
    const float* __restrict__ bias, void* __restrict__ C,
    int N, int K, int lda, int ldb, int ldc,
    long aBatch, long bBatch, long cBatch, float scale) {
    __shared__ __align__(16) unsigned short As[2][4096]; // [128][32] x2
    __shared__ __align__(16) unsigned short Bs[2][4096];
    const int tid  = threadIdx.x;
    const int wave = tid >> 6;
    const int lane = tid & 63;
    const long z = blockIdx.z;
    A  += z * aBatch;
    BT += z * bBatch;
    const int row0 = blockIdx.y * 128;
    const int col0 = blockIdx.x * 128;
    const int wr = (wave >> 1) * 64;
    const int wc = (wave & 1) * 64;

    f32x4 acc[4][4] = {};

    // staging: flat elem = tid*8 (+ c*2048). row = elem/32, col = elem%32
    const unsigned short* Ag = A  + (long)(row0 + (tid >> 2)) * lda + (tid & 3) * 8;
    const unsigned short* Bg = BT + (long)(col0 + (tid >> 2)) * ldb + (tid & 3) * 8;
    const int sBase = wave * 512; // + c*2048

    const int lr  = lane & 15;
    const int kq8 = (lane >> 4) * 8;
    const int nk = K >> 5;

    // prologue: stage K-tile 0 into buf 0
    #pragma unroll
    for (int c = 0; c < 2; ++c) {
        gload_lds16(Ag + (long)c * 64 * lda, &As[0][sBase + c * 2048]);
        gload_lds16(Bg + (long)c * 64 * ldb, &Bs[0][sBase + c * 2048]);
    }
    __syncthreads();

    for (int t = 0; t < nk; ++t) {
        const int cur = t & 1;
        if (t + 1 < nk) {
            const int k0 = (t + 1) << 5;
            #pragma unroll
            for (int c = 0; c < 2; ++c) {
                gload_lds16(Ag + (long)c * 64 * lda + k0, &As[cur ^ 1][sBase + c * 2048]);
                gload_lds16(Bg + (long)c * 64 * ldb + k0, &Bs[cur ^ 1][sBase + c * 2048]);
            }
        }
        short8 af[4], bf[4];
        #pragma unroll
        for (int m = 0; m < 4; ++m)
            af[m] = *(const short8*)&As[cur][(wr + m * 16 + lr) * 32 + kq8];
        #pragma unroll
        for (int n = 0; n < 4; ++n)
            bf[n] = *(const short8*)&Bs[cur][(wc + n * 16 + lr) * 32 + kq8];
        #pragma unroll
        for (int m = 0; m < 4; ++m)
            #pragma unroll
            for (int n = 0; n < 4; ++n)
                acc[m][n] = __builtin_amdgcn_mfma_f32_16x16x32_bf16(
                    af[m], bf[n], acc[m][n], 0, 0, 0);
        __syncthreads();
    }

    // epilogue: C/D layout col=lane&15, row=(lane>>4)*4+reg
    const int orow = row0 + wr + (lane >> 4) * 4;
    const int ocol = col0 + wc + lr;
    const long cb = z * cBatch;
    #pragma unroll
    for (int n = 0; n < 4; ++n) {
        const int cc = ocol + n * 16;
        float bv = 0.0f;
        if (BIAS) bv = bias[cc];
        #pragma unroll
        for (int m = 0; m < 4; ++m) {
            #pragma unroll
            for (int j = 0; j < 4; ++j) {
                float v = acc[m][n][j] * scale + bv;
                if (RELU) v = fmaxf(v, 0.0f);
                long off = cb + (long)(orow + m * 16 + j) * ldc + cc;
                if (OUT_BF16) ((unsigned short*)C)[off] = f2bf(v);
                else          ((float*)C)[off] = v;
            }
        }
    }
}

// ---------------------------------------------------------------------------
// softmax over rows of 2048 (scale already applied). fp32 in -> bf16 out.
// 256 threads/row, each 8 elems.
// ---------------------------------------------------------------------------
__global__ __launch_bounds__(256) void softmax_rows(
    const float* __restrict__ S, unsigned short* __restrict__ P) {
    long row = blockIdx.x;
    const float4* src = (const float4*)(S + row * 2048);
    int tid = threadIdx.x;
    int wave = tid >> 6, lane = tid & 63;
    float4 a = src[tid], b = src[tid + 256];
    float e[8] = { a.x, a.y, a.z, a.w, b.x, b.y, b.z, b.w };
    float m = e[0];
    #pragma unroll
    for (int i = 1; i < 8; ++i) m = fmaxf(m, e[i]);
    #pragma unroll
    for (int o = 32; o > 0; o >>= 1) m = fmaxf(m, __shfl_xor(m, o));
    __shared__ float redm[4], reds[4];
    if (lane == 0) redm[wave] = m;
    __syncthreads();
    m = fmaxf(fmaxf(redm[0], redm[1]), fmaxf(redm[2], redm[3]));
    float s = 0.0f;
    #pragma unroll
    for (int i = 0; i < 8; ++i) { e[i] = __expf(e[i] - m); s += e[i]; }
    #pragma unroll
    for (int o = 32; o > 0; o >>= 1) s += __shfl_xor(s, o);
    if (lane == 0) reds[wave] = s;
    __syncthreads();
    s = reds[0] + reds[1] + reds[2] + reds[3];
    float inv = 1.0f / s;
    ushort4 o0, o1;
    o0.x = f2bf(e[0] * inv); o0.y = f2bf(e[1] * inv);
    o0.z = f2bf(e[2] * inv); o0.w = f2bf(e[3] * inv);
    o1.x = f2bf(e[4] * inv); o1.y = f2bf(e[5] * inv);
    o1.z = f2bf(e[6] * inv); o1.w = f2bf(e[7] * inv);
    ushort4* dst = (ushort4*)(P + row * 2048);
    dst[tid] = o0;
    dst[tid + 256] = o1;
}

// ---------------------------------------------------------------------------
// residual + LayerNorm over rows of 512. optional dual fp32+bf16 output.
// 128 threads/row, each float4.
// ---------------------------------------------------------------------------
template<int DUAL>
__global__ __launch_bounds__(128) void ln_kernel(
    const float* __restrict__ A, const float* __restrict__ R,
    const float* __restrict__ g, const float* __restrict__ be,
    float* __restrict__ out, unsigned short* __restrict__ outbf) {
    long row = blockIdx.x;
    int tid = threadIdx.x;
    int wave = tid >> 6, lane = tid & 63;
    float4 va = ((const float4*)(A + row * 512))[tid];
    float4 vr = ((const float4*)(R + row * 512))[tid];
    float4 v;
    v.x = va.x + vr.x; v.y = va.y + vr.y; v.z = va.z + vr.z; v.w = va.w + vr.w;
    float s  = v.x + v.y + v.z + v.w;
    float s2 = v.x * v.x + v.y * v.y + v.z * v.z + v.w * v.w;
    #pragma unroll
    for (int o = 32; o > 0; o >>= 1) { s += __shfl_xor(s, o); s2 += __shfl_xor(s2, o); }
    __shared__ float r1[2], r2[2];
    if (lane == 0) { r1[wave] = s; r2[wave] = s2; }
    __syncthreads();
    s = r1[0] + r1[1]; s2 = r2[0] + r2[1];
    float mu = s * (1.0f / 512.0f);
    float var = s2 * (1.0f / 512.0f) - mu * mu;
    float rs = rsqrtf(var + 1e-5f);
    float4 gg = ((const float4*)g)[tid];
    float4 bb = ((const float4*)be)[tid];
    float4 y;
    y.x = (v.x - mu) * rs * gg.x + bb.x;
    y.y = (v.y - mu) * rs * gg.y + bb.y;
    y.z = (v.z - mu) * rs * gg.z + bb.z;
    y.w = (v.w - mu) * rs * gg.w + bb.w;
    ((float4*)(out + row * 512))[tid] = y;
    if (DUAL) {
        ushort4 o;
        o.x = f2bf(y.x); o.y = f2bf(y.y); o.z = f2bf(y.z); o.w = f2bf(y.w);
        ((ushort4*)(outbf + row * 512))[tid] = o;
    }
}

// ---------------------------------------------------------------------------
extern "C" void kernel_launch(void* const* d_in, const int* in_sizes, int n_in,
                              void* d_out, int out_size, void* d_ws, size_t ws_size,
                              hipStream_t stream) {
    const float* q   = (const float*)d_in[0];
    const float* k   = (const float*)d_in[1];
    const float* v   = (const float*)d_in[2];
    const float* x   = (const float*)d_in[3];
    const float* Wq  = (const float*)d_in[4];
    const float* bq  = (const float*)d_in[5];
    const float* Wk  = (const float*)d_in[6];
    const float* bk  = (const float*)d_in[7];
    const float* Wv  = (const float*)d_in[8];
    const float* bv  = (const float*)d_in[9];
    const float* g1  = (const float*)d_in[10];
    const float* be1 = (const float*)d_in[11];
    const float* W1  = (const float*)d_in[12];
    const float* b1  = (const float*)d_in[13];
    const float* W2  = (const float*)d_in[14];
    const float* b2  = (const float*)d_in[15];
    const float* g2  = (const float*)d_in[16];
    const float* be2 = (const float*)d_in[17];
    float* out = (float*)d_out;

    const int B = 4, S = 2048, D = 512, F = 2048;
    const long BS = (long)B * S;             // 8192
    const long SD = (long)S * D;             // 1048576 per batch
    const long SS = (long)S * S;             // 4194304 per batch

    char* ws = (char*)d_ws;
    size_t off = 0;
    auto alloc = [&](size_t bytes) -> void* {
        void* p = ws + off;
        off += (bytes + 255) & ~(size_t)255;
        return p;
    };
    // weights bf16 (persistent)
    unsigned short* WqT = (unsigned short*)alloc((size_t)D * D * 2);
    unsigned short* WkT = (unsigned short*)alloc((size_t)D * D * 2);
    unsigned short* WvT = (unsigned short*)alloc((size_t)D * D * 2);
    unsigned short* W1T = (unsigned short*)alloc((size_t)D * F * 2);  // [F][D]
    unsigned short* W2T = (unsigned short*)alloc((size_t)F * D * 2);  // [D][F]
    // R1: q/k/v bf16 casts -> later attn fp32
    unsigned short* qb = (unsigned short*)alloc(BS * D * 2);
    unsigned short* kb = (unsigned short*)alloc(BS * D * 2);
    unsigned short* vb = (unsigned short*)alloc(BS * D * 2);
    float* attn = (float*)qb;                 // 16.8MB <= 25.2MB, reuse after stage 2
    // R2: Q/K/V bf16 -> later h fp32 + h bf16
    unsigned short* Qb = (unsigned short*)alloc(BS * D * 2);
    unsigned short* Kb = (unsigned short*)alloc(BS * D * 2);
    unsigned short* Vb = (unsigned short*)alloc(BS * D * 2);
    float* h_f32 = (float*)Qb;                // 16.8MB (over Qb+Kb)
    unsigned short* h_bf = Vb;                // 8.4MB
    // R3: V^T bf16
    unsigned short* VT = (unsigned short*)alloc(BS * D * 2);
    // R4: scores fp32 -> later f bf16 + f2 fp32
    float* Sc = (float*)alloc((size_t)B * SS * 4);
    unsigned short* f_bf = (unsigned short*)Sc;                 // 33.5MB
    float* f2 = (float*)((char*)Sc + (size_t)BS * F * 2);       // 16.8MB
    // R5: P bf16
    unsigned short* Pb = (unsigned short*)alloc((size_t)B * SS * 2);

    const float scale = 0.04419417382415922f;  // 1/sqrt(512)

    // 1. casts
    {
        long n4 = BS * D / 4;
        int blocks = (int)((n4 + 255) / 256);
        cast_f32_bf16<<<blocks, 256, 0, stream>>>(q, qb, n4);
        cast_f32_bf16<<<blocks, 256, 0, stream>>>(k, kb, n4);
        cast_f32_bf16<<<blocks, 256, 0, stream>>>(v, vb, n4);
    }
    // 2. weight transposes
    transpose_cast_f32_bf16<<<dim3(D/32, D/32), dim3(32, 8), 0, stream>>>(Wq, WqT, D, D);
    transpose_cast_f32_bf16<<<dim3(D/32, D/32), dim3(32, 8), 0, stream>>>(Wk, WkT, D, D);
    transpose_cast_f32_bf16<<<dim3(D/32, D/32), dim3(32, 8), 0, stream>>>(Wv, WvT, D, D);
    transpose_cast_f32_bf16<<<dim3(F/32, D/32), dim3(32, 8), 0, stream>>>(W1, W1T, D, F);
    transpose_cast_f32_bf16<<<dim3(D/32, F/32), dim3(32, 8), 0, stream>>>(W2, W2T, F, D);
    // 3. QKV projections: [8192,512] = [8192,512] @ [512,512]
    gemm_nt<1,0,1><<<dim3(D/128, BS/128, 1), 256, 0, stream>>>(qb, WqT, bq, Qb, D, D, D, D, D, 0, 0, 0, 1.0f);
    gemm_nt<1,0,1><<<dim3(D/128, BS/128, 1), 256, 0, stream>>>(kb, WkT, bk, Kb, D, D, D, D, D, 0, 0, 0, 1.0f);
    gemm_nt<1,0,1><<<dim3(D/128, BS/128, 1), 256, 0, stream>>>(vb, WvT, bv, Vb, D, D, D, D, D, 0, 0, 0, 1.0f);
    // 4. V transpose per batch: [S,D] -> [D,S]
    transpose_bf16<<<dim3(D/32, S/32, B), dim3(32, 8), 0, stream>>>(Vb, VT, S, D, D, SD, SD);
    // 5. scores: per batch [2048,2048] = scale * Q @ K^T
    gemm_nt<0,0,0><<<dim3(S/128, S/128, B), 256, 0, stream>>>(Qb, Kb, nullptr, Sc, S, D, D, D, S, SD, SD, SS, scale);
    // 6. softmax -> P bf16
    softmax_rows<<<(int)BS, 256, 0, stream>>>(Sc, Pb);
    // 7. attn = P @ V : per batch [2048,512] = P[2048,2048] @ VT[512,2048]^T
    gemm_nt<0,0,0><<<dim3(D/128, S/128, B), 256, 0, stream>>>(Pb, VT, nullptr, attn, D, S, S, S, D, SS, SD, SD, 1.0f);
    // 8. h = LN(attn + x), dual output
    ln_kernel<1><<<(int)BS, 128, 0, stream>>>(attn, x, g1, be1, h_f32, h_bf);
    // 9. f = relu(h @ W1 + b1): [8192,2048]
    gemm_nt<1,1,1><<<dim3(F/128, BS/128, 1), 256, 0, stream>>>(h_bf, W1T, b1, f_bf, F, D, D, D, F, 0, 0, 0, 1.0f);
    // 10. f2 = f @ W2 + b2: [8192,512]
    gemm_nt<1,0,0><<<dim3(D/128, BS/128, 1), 256, 0, stream>>>(f_bf, W2T, b2, f2, D, F, F, F, D, 0, 0, 0, 1.0f);
    // 11. out = LN(f2 + h)
    ln_kernel<0><<<(int)BS, 128, 0, stream>>>(f2, h_f32, g2, be2, out, nullptr);
}

// Round 4
// 354.740 us; speedup vs baseline: 1.0883x; 1.0883x over previous
//
#include <hip/hip_runtime.h>

// ---------------------------------------------------------------------------
// Encoder layer on MI355X (gfx950). bf16 MFMA GEMMs + fp32 LN/softmax.
// B=4, S=2048, D=512, F=2048.
// Round 3 (resubmit after GPU acquisition timeout): fused QKV (one 768-block
// dispatch), split-K=2 for PV/FFN2 (2 blocks/CU), LDS K-quad XOR swizzle
// (8-way -> 2-way bank conflict).
// ---------------------------------------------------------------------------

typedef __attribute__((ext_vector_type(8))) short short8;
typedef __attribute__((ext_vector_type(4))) float f32x4;

__device__ __forceinline__ unsigned short f2bf(float f) {
    unsigned int u = __float_as_uint(f);
    unsigned int r = (u + 0x7FFFu + ((u >> 16) & 1u)) >> 16;
    return (unsigned short)r;
}

__device__ __forceinline__ void gload_lds16(const void* g, void* l) {
    __builtin_amdgcn_global_load_lds(
        (const __attribute__((address_space(1))) void*)g,
        (__attribute__((address_space(3))) void*)l, 16, 0, 0);
}

// ---------------------------------------------------------------------------
__global__ __launch_bounds__(256) void cast_f32_bf16(
    const float* __restrict__ in, unsigned short* __restrict__ out, long n4) {
    long i = (long)blockIdx.x * blockDim.x + threadIdx.x;
    if (i < n4) {
        float4 v = ((const float4*)in)[i];
        ushort4 o;
        o.x = f2bf(v.x); o.y = f2bf(v.y); o.z = f2bf(v.z); o.w = f2bf(v.w);
        ((ushort4*)out)[i] = o;
    }
}

// concat three [n] fp32 vectors
__global__ __launch_bounds__(256) void concat3(
    const float* __restrict__ a, const float* __restrict__ b,
    const float* __restrict__ c, float* __restrict__ o, int n) {
    int i = blockIdx.x * blockDim.x + threadIdx.x;
    if (i < n) o[i] = a[i];
    else if (i < 2 * n) o[i] = b[i - n];
    else if (i < 3 * n) o[i] = c[i - 2 * n];
}

// ---------------------------------------------------------------------------
// transpose + cast: fp32 in[R][C] -> bf16 out[C][R]
// ---------------------------------------------------------------------------
__global__ __launch_bounds__(256) void transpose_cast_f32_bf16(
    const float* __restrict__ in, unsigned short* __restrict__ out, int R, int C) {
    __shared__ float t[32][33];
    int c0 = blockIdx.x * 32, r0 = blockIdx.y * 32;
    int x = threadIdx.x;
    for (int i = threadIdx.y; i < 32; i += 8)
        t[i][x] = in[(long)(r0 + i) * C + c0 + x];
    __syncthreads();
    for (int i = threadIdx.y; i < 32; i += 8)
        out[(long)(c0 + i) * R + r0 + x] = f2bf(t[x][i]);
}

// ---------------------------------------------------------------------------
// transpose bf16: in[R][C] (row stride inLd) -> out[C][R], batched over z
// ---------------------------------------------------------------------------
__global__ __launch_bounds__(256) void transpose_bf16(
    const unsigned short* __restrict__ in, unsigned short* __restrict__ out,
    int R, int C, int inLd, long inBatch, long outBatch) {
    __shared__ unsigned short t[32][33];
    long z = blockIdx.z;
    in += z * inBatch; out += z * outBatch;
    int c0 = blockIdx.x * 32, r0 = blockIdx.y * 32;
    int x = threadIdx.x;
    for (int i = threadIdx.y; i < 32; i += 8)
        t[i][x] = in[(long)(r0 + i) * inLd + c0 + x];
    __syncthreads();
    for (int i = threadIdx.y; i < 32; i += 8)
        out[(long)(c0 + i) * R + r0 + x] = t[x][i];
}

// ---------------------------------------------------------------------------
// bf16 nt-GEMM: C = scale*(A[.,K] * BT[.,K]^T) + bias, opt relu.
// 128x128 tile, BK=32, 4 waves, each wave 64x64 (4x4 16x16x32 MFMA frags).
// Double-buffered global_load_lds staging. LDS K-quad XOR swizzle:
// slot q -> q ^ (r&3) ^ ((r>>2)&3) applied on the GLOBAL source address
// (gload_lds dest must stay linear) and on the ds_read address.
// z decomposes as (b, kc): b = z/zDiv (batch), kc = z%zDiv (K-split chunk).
// aGroup: QKV-fusion hack — A += (col0>>9)*aGroup selects q/k/v per N-group.
// ---------------------------------------------------------------------------
template<int BIAS, int RELU, int OUT_BF16>
__global__ __launch_bounds__(256, 2) void gemm_nt(
    const unsigned short* __restrict__ A, const unsigned short* __restrict__ BT,
    const float* __restrict__ bias, void* __restrict__ C,
    int K, int lda, int ldb, int ldc,
    long aBatch, long bBatch, long cBatch,
    long aKOff, long bKOff, long cKOff, int zDiv,
    long aGroup, float scale) {
    __shared__ __align__(16) unsigned short As[2][4096]; // [128][32] x2
    __shared__ __align__(16) unsigned short Bs[2][4096];
    const int tid  = threadIdx.x;
    const int wave = tid >> 6;
    const int lane = tid & 63;
    const int z = blockIdx.z;
    const int b = z / zDiv;
    const int kc = z - b * zDiv;
    const int row0 = blockIdx.y * 128;
    const int col0 = blockIdx.x * 128;
    A  += (long)b * aBatch + (long)kc * aKOff + (long)(col0 >> 9) * aGroup;
    BT += (long)b * bBatch + (long)kc * bKOff;
    const long cOff = (long)b * cBatch + (long)kc * cKOff;
    const int wr = (wave >> 1) * 64;
    const int wc = (wave & 1) * 64;

    f32x4 acc[4][4] = {};

    // staging: thread -> LDS slot (r = tid>>2 + c*64, q = tid&3); source
    // pre-swizzled so LDS(r,q) holds global (r, q ^ f(r)).
    const int fs = ((tid >> 2) & 3) ^ ((tid >> 4) & 3);
    const unsigned short* Ag = A  + (long)(row0 + (tid >> 2)) * lda + (((tid & 3) ^ fs) << 3);
    const unsigned short* Bg = BT + (long)(col0 + (tid >> 2)) * ldb + (((tid & 3) ^ fs) << 3);
    const int sBase = wave * 512; // + c*2048

    const int lr  = lane & 15;
    const int fr  = (lr & 3) ^ ((lr >> 2) & 3);
    const int kq8 = (((lane >> 4) ^ fr) << 3);
    const int nk = K >> 5;

    // prologue: stage K-tile 0 into buf 0
    #pragma unroll
    for (int c = 0; c < 2; ++c) {
        gload_lds16(Ag + (long)c * 64 * lda, &As[0][sBase + c * 2048]);
        gload_lds16(Bg + (long)c * 64 * ldb, &Bs[0][sBase + c * 2048]);
    }
    __syncthreads();

    for (int t = 0; t < nk; ++t) {
        const int cur = t & 1;
        if (t + 1 < nk) {
            const int k0 = (t + 1) << 5;
            #pragma unroll
            for (int c = 0; c < 2; ++c) {
                gload_lds16(Ag + (long)c * 64 * lda + k0, &As[cur ^ 1][sBase + c * 2048]);
                gload_lds16(Bg + (long)c * 64 * ldb + k0, &Bs[cur ^ 1][sBase + c * 2048]);
            }
        }
        short8 af[4], bf[4];
        #pragma unroll
        for (int m = 0; m < 4; ++m)
            af[m] = *(const short8*)&As[cur][(wr + m * 16 + lr) * 32 + kq8];
        #pragma unroll
        for (int n = 0; n < 4; ++n)
            bf[n] = *(const short8*)&Bs[cur][(wc + n * 16 + lr) * 32 + kq8];
        #pragma unroll
        for (int m = 0; m < 4; ++m)
            #pragma unroll
            for (int n = 0; n < 4; ++n)
                acc[m][n] = __builtin_amdgcn_mfma_f32_16x16x32_bf16(
                    af[m], bf[n], acc[m][n], 0, 0, 0);
        __syncthreads();
    }

    // epilogue: C/D layout col=lane&15, row=(lane>>4)*4+reg
    const int orow = row0 + wr + (lane >> 4) * 4;
    const int ocol = col0 + wc + lr;
    #pragma unroll
    for (int n = 0; n < 4; ++n) {
        const int cc = ocol + n * 16;
        float bv = 0.0f;
        if (BIAS) bv = bias[cc];
        #pragma unroll
        for (int m = 0; m < 4; ++m) {
            #pragma unroll
            for (int j = 0; j < 4; ++j) {
                float v = acc[m][n][j] * scale + bv;
                if (RELU) v = fmaxf(v, 0.0f);
                long off = cOff + (long)(orow + m * 16 + j) * ldc + cc;
                if (OUT_BF16) ((unsigned short*)C)[off] = f2bf(v);
                else          ((float*)C)[off] = v;
            }
        }
    }
}

// ---------------------------------------------------------------------------
// softmax over rows of 2048 (scale already applied). fp32 in -> bf16 out.
// ---------------------------------------------------------------------------
__global__ __launch_bounds__(256) void softmax_rows(
    const float* __restrict__ S, unsigned short* __restrict__ P) {
    long row = blockIdx.x;
    const float4* src = (const float4*)(S + row * 2048);
    int tid = threadIdx.x;
    int wave = tid >> 6, lane = tid & 63;
    float4 a = src[tid], b = src[tid + 256];
    float e[8] = { a.x, a.y, a.z, a.w, b.x, b.y, b.z, b.w };
    float m = e[0];
    #pragma unroll
    for (int i = 1; i < 8; ++i) m = fmaxf(m, e[i]);
    #pragma unroll
    for (int o = 32; o > 0; o >>= 1) m = fmaxf(m, __shfl_xor(m, o));
    __shared__ float redm[4], reds[4];
    if (lane == 0) redm[wave] = m;
    __syncthreads();
    m = fmaxf(fmaxf(redm[0], redm[1]), fmaxf(redm[2], redm[3]));
    float s = 0.0f;
    #pragma unroll
    for (int i = 0; i < 8; ++i) { e[i] = __expf(e[i] - m); s += e[i]; }
    #pragma unroll
    for (int o = 32; o > 0; o >>= 1) s += __shfl_xor(s, o);
    if (lane == 0) reds[wave] = s;
    __syncthreads();
    s = reds[0] + reds[1] + reds[2] + reds[3];
    float inv = 1.0f / s;
    ushort4 o0, o1;
    o0.x = f2bf(e[0] * inv); o0.y = f2bf(e[1] * inv);
    o0.z = f2bf(e[2] * inv); o0.w = f2bf(e[3] * inv);
    o1.x = f2bf(e[4] * inv); o1.y = f2bf(e[5] * inv);
    o1.z = f2bf(e[6] * inv); o1.w = f2bf(e[7] * inv);
    ushort4* dst = (ushort4*)(P + row * 2048);
    dst[tid] = o0;
    dst[tid + 256] = o1;
}

// ---------------------------------------------------------------------------
// residual + LayerNorm over rows of 512, summing NPART partial fp32 inputs
// (+ optional column bias). optional dual fp32+bf16 output.
// A1 = A0 + partOff when NPART==2.
// ---------------------------------------------------------------------------
template<int NPART, int BIASF, int DUAL>
__global__ __launch_bounds__(128) void ln_kernel(
    const float* __restrict__ A0, long partOff, const float* __restrict__ R,
    const float* __restrict__ bias,
    const float* __restrict__ g, const float* __restrict__ be,
    float* __restrict__ out, unsigned short* __restrict__ outbf) {
    long row = blockIdx.x;
    int tid = threadIdx.x;
    int wave = tid >> 6, lane = tid & 63;
    float4 va = ((const float4*)(A0 + row * 512))[tid];
    float4 vr = ((const float4*)(R + row * 512))[tid];
    float4 v;
    v.x = va.x + vr.x; v.y = va.y + vr.y; v.z = va.z + vr.z; v.w = va.w + vr.w;
    if (NPART == 2) {
        float4 vp = ((const float4*)(A0 + partOff + row * 512))[tid];
        v.x += vp.x; v.y += vp.y; v.z += vp.z; v.w += vp.w;
    }
    if (BIASF) {
        float4 vb = ((const float4*)bias)[tid];
        v.x += vb.x; v.y += vb.y; v.z += vb.z; v.w += vb.w;
    }
    float s  = v.x + v.y + v.z + v.w;
    float s2 = v.x * v.x + v.y * v.y + v.z * v.z + v.w * v.w;
    #pragma unroll
    for (int o = 32; o > 0; o >>= 1) { s += __shfl_xor(s, o); s2 += __shfl_xor(s2, o); }
    __shared__ float r1[2], r2[2];
    if (lane == 0) { r1[wave] = s; r2[wave] = s2; }
    __syncthreads();
    s = r1[0] + r1[1]; s2 = r2[0] + r2[1];
    float mu = s * (1.0f / 512.0f);
    float var = s2 * (1.0f / 512.0f) - mu * mu;
    float rs = rsqrtf(var + 1e-5f);
    float4 gg = ((const float4*)g)[tid];
    float4 bb = ((const float4*)be)[tid];
    float4 y;
    y.x = (v.x - mu) * rs * gg.x + bb.x;
    y.y = (v.y - mu) * rs * gg.y + bb.y;
    y.z = (v.z - mu) * rs * gg.z + bb.z;
    y.w = (v.w - mu) * rs * gg.w + bb.w;
    ((float4*)(out + row * 512))[tid] = y;
    if (DUAL) {
        ushort4 o;
        o.x = f2bf(y.x); o.y = f2bf(y.y); o.z = f2bf(y.z); o.w = f2bf(y.w);
        ((ushort4*)(outbf + row * 512))[tid] = o;
    }
}

// ---------------------------------------------------------------------------
extern "C" void kernel_launch(void* const* d_in, const int* in_sizes, int n_in,
                              void* d_out, int out_size, void* d_ws, size_t ws_size,
                              hipStream_t stream) {
    const float* q   = (const float*)d_in[0];
    const float* k   = (const float*)d_in[1];
    const float* v   = (const float*)d_in[2];
    const float* x   = (const float*)d_in[3];
    const float* Wq  = (const float*)d_in[4];
    const float* bq  = (const float*)d_in[5];
    const float* Wk  = (const float*)d_in[6];
    const float* bk  = (const float*)d_in[7];
    const float* Wv  = (const float*)d_in[8];
    const float* bv  = (const float*)d_in[9];
    const float* g1  = (const float*)d_in[10];
    const float* be1 = (const float*)d_in[11];
    const float* W1  = (const float*)d_in[12];
    const float* b1  = (const float*)d_in[13];
    const float* W2  = (const float*)d_in[14];
    const float* b2  = (const float*)d_in[15];
    const float* g2  = (const float*)d_in[16];
    const float* be2 = (const float*)d_in[17];
    float* out = (float*)d_out;

    const int B = 4, S = 2048, D = 512, F = 2048;
    const long BS = (long)B * S;             // 8192
    const long SD = (long)S * D;             // 1048576 per batch
    const long SS = (long)S * S;             // 4194304 per batch
    const int N3 = 3 * D;                    // 1536

    char* ws = (char*)d_ws;
    size_t off = 0;
    auto alloc = [&](size_t bytes) -> void* {
        void* p = ws + off;
        off += (bytes + 255) & ~(size_t)255;
        return p;
    };
    // persistent weights
    unsigned short* WqkvT = (unsigned short*)alloc((size_t)N3 * D * 2); // [1536][512]
    unsigned short* W1T   = (unsigned short*)alloc((size_t)D * F * 2);  // [F][D]
    unsigned short* W2T   = (unsigned short*)alloc((size_t)F * D * 2);  // [D][F]
    float* bqkv           = (float*)alloc((size_t)N3 * 4);
    // R1: qkv_in bf16 (q,k,v contiguous) -> later VT
    unsigned short* qkv_in = (unsigned short*)alloc(3 * BS * D * 2);    // 25.2MB
    unsigned short* VT = qkv_in;                                        // 8.4MB
    // R2: QKV bf16 [8192][1536] -> later h_f32 + h_bf
    unsigned short* QKV = (unsigned short*)alloc(BS * (size_t)N3 * 2);  // 25.2MB
    float* h_f32 = (float*)QKV;                                         // 16.8MB
    unsigned short* h_bf = (unsigned short*)((char*)QKV + BS * D * 4);  // 8.4MB
    // R3: Sc fp32 -> later attnP (2x) -> later f2P (2x)
    float* Sc = (float*)alloc((size_t)B * SS * 4);                      // 67MB
    float* attnP = Sc;                                                  // 2 x 16.8MB
    float* f2P   = Sc;                                                  // 2 x 16.8MB
    // R4: Pb bf16 -> later f_bf
    unsigned short* Pb = (unsigned short*)alloc((size_t)B * SS * 2);    // 33.5MB
    unsigned short* f_bf = Pb;                                          // 33.5MB

    const float scale = 0.04419417382415922f;  // 1/sqrt(512)

    // 1. casts q,k,v -> bf16 (contiguous)
    {
        long n4 = BS * D / 4;
        int blocks = (int)((n4 + 255) / 256);
        cast_f32_bf16<<<blocks, 256, 0, stream>>>(q, qkv_in, n4);
        cast_f32_bf16<<<blocks, 256, 0, stream>>>(k, qkv_in + BS * D, n4);
        cast_f32_bf16<<<blocks, 256, 0, stream>>>(v, qkv_in + 2 * BS * D, n4);
    }
    // 2. weight transposes + bias concat
    transpose_cast_f32_bf16<<<dim3(D/32, D/32), dim3(32, 8), 0, stream>>>(Wq, WqkvT, D, D);
    transpose_cast_f32_bf16<<<dim3(D/32, D/32), dim3(32, 8), 0, stream>>>(Wk, WqkvT + (size_t)D * D, D, D);
    transpose_cast_f32_bf16<<<dim3(D/32, D/32), dim3(32, 8), 0, stream>>>(Wv, WqkvT + 2 * (size_t)D * D, D, D);
    transpose_cast_f32_bf16<<<dim3(F/32, D/32), dim3(32, 8), 0, stream>>>(W1, W1T, D, F);
    transpose_cast_f32_bf16<<<dim3(D/32, F/32), dim3(32, 8), 0, stream>>>(W2, W2T, F, D);
    concat3<<<(3 * D + 255) / 256, 256, 0, stream>>>(bq, bk, bv, bqkv, D);
    // 3. fused QKV projection: [8192,1536], A selected per 512-col group
    gemm_nt<1,0,1><<<dim3(N3/128, BS/128, 1), 256, 0, stream>>>(
        qkv_in, WqkvT, bqkv, QKV, D, D, D, N3,
        0, 0, 0, 0, 0, 0, 1, BS * D, 1.0f);
    // 4. V transpose per batch: QKV cols 1024..1535 -> VT[b][512][2048]
    transpose_bf16<<<dim3(D/32, S/32, B), dim3(32, 8), 0, stream>>>(
        QKV + 2 * D, VT, S, D, N3, (long)S * N3, SD);
    // 5. scores: per batch [2048,2048] = scale * Q @ K^T
    gemm_nt<0,0,0><<<dim3(S/128, S/128, B), 256, 0, stream>>>(
        QKV, QKV + D, nullptr, Sc, D, N3, N3, S,
        (long)S * N3, (long)S * N3, SS, 0, 0, 0, 1, 0, scale);
    // 6. softmax -> P bf16
    softmax_rows<<<(int)BS, 256, 0, stream>>>(Sc, Pb);
    // 7. attn = P @ V, split-K=2: z=(b,kc), partials attnP[kc][b][2048][512]
    gemm_nt<0,0,0><<<dim3(D/128, S/128, 2 * B), 256, 0, stream>>>(
        Pb, VT, nullptr, attnP, S / 2, S, S, D,
        SS, SD, SD, S / 2, S / 2, BS * D, 2, 0, 1.0f);
    // 8. h = LN(attnP0 + attnP1 + x), dual output
    ln_kernel<2,0,1><<<(int)BS, 128, 0, stream>>>(attnP, BS * D, x, nullptr, g1, be1, h_f32, h_bf);
    // 9. f = relu(h @ W1 + b1): [8192,2048]
    gemm_nt<1,1,1><<<dim3(F/128, BS/128, 1), 256, 0, stream>>>(
        h_bf, W1T, b1, f_bf, D, D, D, F,
        0, 0, 0, 0, 0, 0, 1, 0, 1.0f);
    // 10. f2 partials = f @ W2, split-K=2 (b2 folded into LN2)
    gemm_nt<0,0,0><<<dim3(D/128, BS/128, 2), 256, 0, stream>>>(
        f_bf, W2T, nullptr, f2P, F / 2, F, F, D,
        0, 0, 0, F / 2, F / 2, BS * D, 2, 0, 1.0f);
    // 11. out = LN(f2P0 + f2P1 + b2 + h)
    ln_kernel<2,1,0><<<(int)BS, 128, 0, stream>>>(f2P, BS * D, h_f32, b2, g2, be2, out, nullptr);
}